// Round 1
// baseline (425.027 us; speedup 1.0000x reference)
//
#include <hip/hip_runtime.h>
#include <hip/hip_bf16.h>

// Problem constants (fixed by the reference)
#define T_SEQ 4096
#define C_EMB 768
#define NH_ 12
#define HS_ 64
#define B_SZ 2
#define M_TOK 8192        // B*T
#define N_QKV 2304        // 3*C

typedef __attribute__((ext_vector_type(8))) __bf16 bf16x8;
typedef __attribute__((ext_vector_type(8))) unsigned short ushort8v;
typedef __attribute__((ext_vector_type(4))) unsigned int uint4v;
typedef __attribute__((ext_vector_type(4))) float f32x4;

__device__ __forceinline__ unsigned short f2bf(float f) {
  __hip_bfloat16 h = __float2bfloat16(f);
  return __builtin_bit_cast(unsigned short, h);
}

__device__ __forceinline__ unsigned int pack2bf(float lo, float hi) {
  return ((unsigned int)f2bf(hi) << 16) | (unsigned int)f2bf(lo);
}

__device__ __forceinline__ bf16x8 lds_frag(const unsigned short* p) {
  return __builtin_bit_cast(bf16x8, *reinterpret_cast<const ushort8v*>(p));
}

// ---------------------------------------------------------------- converts
__global__ void cvt_f32_bf16(const float* __restrict__ in,
                             unsigned short* __restrict__ out) {
  int i = (blockIdx.x * 256 + threadIdx.x) * 4;
  float4 v = *reinterpret_cast<const float4*>(&in[i]);
  ushort4 o;
  o.x = f2bf(v.x); o.y = f2bf(v.y); o.z = f2bf(v.z); o.w = f2bf(v.w);
  *reinterpret_cast<ushort4*>(&out[i]) = o;
}

// ---------------------------------------------------------------- GEMM (B^T)
// C[M][N] = A[M][K] * Bw[N][K]^T + bias.  128x128 tile, 4 waves, BK=64.
// MODE 0: scatter into Q/K/V [bh][t][64] bf16 (Q scaled by 0.125)
// MODE 1: fp32 out row-major [M][N]
template <int MODE>
__global__ __launch_bounds__(256) void gemm_bt_kernel(
    const unsigned short* __restrict__ A, const unsigned short* __restrict__ Bw,
    const float* __restrict__ bias, unsigned short* __restrict__ qo,
    unsigned short* __restrict__ ko, unsigned short* __restrict__ vo,
    float* __restrict__ fo, int Kdim, int Ndim) {
  __shared__ unsigned short as_[128 * 72];  // +8 pad: 2-way banks on frag reads
  __shared__ unsigned short bs_[128 * 72];
  const int tid = threadIdx.x;
  const int lane = tid & 63;
  const int wid = tid >> 6;
  const int g = lane >> 4;
  const int l15 = lane & 15;
  const int m0 = blockIdx.y * 128;
  const int n0 = blockIdx.x * 128;
  const int wm = (wid >> 1) * 64;
  const int wn = (wid & 1) * 64;

  f32x4 acc[4][4];
#pragma unroll
  for (int i = 0; i < 4; ++i)
#pragma unroll
    for (int j = 0; j < 4; ++j) acc[i][j] = (f32x4){0.f, 0.f, 0.f, 0.f};

  for (int k0 = 0; k0 < Kdim; k0 += 64) {
#pragma unroll
    for (int it = 0; it < 4; ++it) {
      int cid = tid + it * 256;
      int r = cid >> 3, c8 = (cid & 7) << 3;
      *reinterpret_cast<ushort8v*>(&as_[r * 72 + c8]) =
          *reinterpret_cast<const ushort8v*>(&A[(size_t)(m0 + r) * Kdim + k0 + c8]);
      *reinterpret_cast<ushort8v*>(&bs_[r * 72 + c8]) =
          *reinterpret_cast<const ushort8v*>(&Bw[(size_t)(n0 + r) * Kdim + k0 + c8]);
    }
    __syncthreads();
#pragma unroll
    for (int ks = 0; ks < 2; ++ks) {
      bf16x8 af[4], bfr[4];
#pragma unroll
      for (int mf = 0; mf < 4; ++mf)
        af[mf] = lds_frag(&as_[(wm + mf * 16 + l15) * 72 + ks * 32 + g * 8]);
#pragma unroll
      for (int nf = 0; nf < 4; ++nf)
        bfr[nf] = lds_frag(&bs_[(wn + nf * 16 + l15) * 72 + ks * 32 + g * 8]);
#pragma unroll
      for (int mf = 0; mf < 4; ++mf)
#pragma unroll
        for (int nf = 0; nf < 4; ++nf)
          acc[mf][nf] = __builtin_amdgcn_mfma_f32_16x16x32_bf16(
              af[mf], bfr[nf], acc[mf][nf], 0, 0, 0);
    }
    __syncthreads();
  }

#pragma unroll
  for (int mf = 0; mf < 4; ++mf)
#pragma unroll
    for (int nf = 0; nf < 4; ++nf) {
      const int n = n0 + wn + nf * 16 + l15;
      const float bval = bias[n];
#pragma unroll
      for (int r2 = 0; r2 < 4; ++r2) {
        const int m = m0 + wm + mf * 16 + g * 4 + r2;
        float val = acc[mf][nf][r2] + bval;
        if (MODE == 0) {
          const int which = (n >= 1536) ? 2 : ((n >= 768) ? 1 : 0);
          const int c = n - which * 768;
          const int h = c >> 6, d = c & 63;
          const int bI = m >> 12, t = m & 4095;
          const size_t off = ((size_t)(bI * NH_ + h) * T_SEQ + t) * HS_ + d;
          if (which == 0) qo[off] = f2bf(val * 0.125f);       // fold SCALE into Q
          else if (which == 1) ko[off] = f2bf(val);
          else vo[off] = f2bf(val);
        } else {
          fo[(size_t)m * Ndim + n] = val;
        }
      }
    }
}

// ---------------------------------------------------------------- flash attn
// Per block: 128 q-rows of one (b,h); 4 waves x 32 rows. KV tiles of 64.
// Swapped QK^T: St = mfma(K, Q) -> St[tk][tq]; softmax over tk is per-lane
// local (16 vals) + shfl_xor(16,32). P moved to PV A-frags via packed shfl.
__global__ __launch_bounds__(256) void flash_kernel(
    const unsigned short* __restrict__ Qg, const unsigned short* __restrict__ Kg,
    const unsigned short* __restrict__ Vg, unsigned short* __restrict__ Og) {
  __shared__ unsigned short qs[128 * 72];
  __shared__ unsigned short ksm[64 * 72];
  __shared__ unsigned short vsm[64 * 72];
  const int tid = threadIdx.x;
  const int lane = tid & 63;
  const int wid = tid >> 6;
  const int g = lane >> 4;
  const int l15 = lane & 15;
  const int q0 = blockIdx.x * 128;
  const int bh = blockIdx.y;
  const size_t base = (size_t)bh * T_SEQ * HS_;
  const int b_ = bh / NH_, h_ = bh % NH_;
  const int wq0 = wid * 32;

#pragma unroll
  for (int it = 0; it < 4; ++it) {
    int cid = tid + it * 256;
    int r = cid >> 3, c8 = (cid & 7) << 3;
    *reinterpret_cast<ushort8v*>(&qs[r * 72 + c8]) =
        *reinterpret_cast<const ushort8v*>(&Qg[base + (size_t)(q0 + r) * HS_ + c8]);
  }

  float m_run[2] = {-1e30f, -1e30f};
  float l_run[2] = {0.f, 0.f};
  f32x4 oacc[2][4];
#pragma unroll
  for (int i = 0; i < 2; ++i)
#pragma unroll
    for (int j = 0; j < 4; ++j) oacc[i][j] = (f32x4){0.f, 0.f, 0.f, 0.f};

  const int nkt = (q0 >> 6) + 2;  // causal: KV tiles up to the diagonal
  for (int kt = 0; kt < nkt; ++kt) {
    const int k0 = kt * 64;
#pragma unroll
    for (int it = 0; it < 2; ++it) {
      int cid = tid + it * 256;
      int r = cid >> 3, c8 = (cid & 7) << 3;
      *reinterpret_cast<ushort8v*>(&ksm[r * 72 + c8]) =
          *reinterpret_cast<const ushort8v*>(&Kg[base + (size_t)(k0 + r) * HS_ + c8]);
      *reinterpret_cast<ushort8v*>(&vsm[r * 72 + c8]) =
          *reinterpret_cast<const ushort8v*>(&Vg[base + (size_t)(k0 + r) * HS_ + c8]);
    }
    __syncthreads();

    // St[tk 64][tq 32-per-wave]: 4 mf x 2 nf frags
    f32x4 st[4][2];
#pragma unroll
    for (int i = 0; i < 4; ++i)
#pragma unroll
      for (int j = 0; j < 2; ++j) st[i][j] = (f32x4){0.f, 0.f, 0.f, 0.f};
#pragma unroll
    for (int ks = 0; ks < 2; ++ks) {
      bf16x8 af[4], qf[2];
#pragma unroll
      for (int mf = 0; mf < 4; ++mf)
        af[mf] = lds_frag(&ksm[(mf * 16 + l15) * 72 + ks * 32 + g * 8]);
#pragma unroll
      for (int nf = 0; nf < 2; ++nf)
        qf[nf] = lds_frag(&qs[(wq0 + nf * 16 + l15) * 72 + ks * 32 + g * 8]);
#pragma unroll
      for (int mf = 0; mf < 4; ++mf)
#pragma unroll
        for (int nf = 0; nf < 2; ++nf)
          st[mf][nf] = __builtin_amdgcn_mfma_f32_16x16x32_bf16(
              af[mf], qf[nf], st[mf][nf], 0, 0, 0);
    }

    if (k0 + 63 > q0 + wq0) {  // causal mask (wave-uniform branch)
#pragma unroll
      for (int mf = 0; mf < 4; ++mf)
#pragma unroll
        for (int nf = 0; nf < 2; ++nf)
#pragma unroll
          for (int r2 = 0; r2 < 4; ++r2) {
            const int tk = k0 + mf * 16 + g * 4 + r2;
            const int tq = q0 + wq0 + nf * 16 + l15;
            if (tk > tq) st[mf][nf][r2] = -1e30f;
          }
    }

    float alpha[2];
#pragma unroll
    for (int nf = 0; nf < 2; ++nf) {
      float mx = -1e30f;
#pragma unroll
      for (int mf = 0; mf < 4; ++mf)
#pragma unroll
        for (int r2 = 0; r2 < 4; ++r2) mx = fmaxf(mx, st[mf][nf][r2]);
      mx = fmaxf(mx, __shfl_xor(mx, 16));
      mx = fmaxf(mx, __shfl_xor(mx, 32));
      const float mnew = fmaxf(m_run[nf], mx);
      alpha[nf] = __expf(m_run[nf] - mnew);
      float ssum = 0.f;
#pragma unroll
      for (int mf = 0; mf < 4; ++mf)
#pragma unroll
        for (int r2 = 0; r2 < 4; ++r2) {
          const float p = __expf(st[mf][nf][r2] - mnew);
          st[mf][nf][r2] = p;
          ssum += p;
        }
      ssum += __shfl_xor(ssum, 16);
      ssum += __shfl_xor(ssum, 32);
      l_run[nf] = l_run[nf] * alpha[nf] + ssum;
      m_run[nf] = mnew;
    }

    // rescale O accumulators (alpha lives at lane (4g+reg) for O-domain rows)
#pragma unroll
    for (int mP = 0; mP < 2; ++mP) {
      float ar[4];
#pragma unroll
      for (int r2 = 0; r2 < 4; ++r2) ar[r2] = __shfl(alpha[mP], g * 4 + r2);
#pragma unroll
      for (int nd = 0; nd < 4; ++nd)
#pragma unroll
        for (int r2 = 0; r2 < 4; ++r2) oacc[mP][nd][r2] *= ar[r2];
    }

    // pack P (bf16 pairs) then shuffle into PV A-fragment layout
    unsigned int pp[4][2][2];
#pragma unroll
    for (int mf = 0; mf < 4; ++mf)
#pragma unroll
      for (int nf = 0; nf < 2; ++nf) {
        pp[mf][nf][0] = pack2bf(st[mf][nf][0], st[mf][nf][1]);
        pp[mf][nf][1] = pack2bf(st[mf][nf][2], st[mf][nf][3]);
      }

    const int sA = l15 + ((g & 1) << 5);
    const int sB = sA + 16;
    const bool upper = (g >= 2);
#pragma unroll
    for (int ks = 0; ks < 2; ++ks) {
      bf16x8 pa[2];
#pragma unroll
      for (int mP = 0; mP < 2; ++mP) {
        unsigned a0 = __shfl(pp[2 * ks][mP][0], sA);
        unsigned a1 = __shfl(pp[2 * ks][mP][1], sA);
        unsigned a2 = __shfl(pp[2 * ks][mP][0], sB);
        unsigned a3 = __shfl(pp[2 * ks][mP][1], sB);
        unsigned b0 = __shfl(pp[2 * ks + 1][mP][0], sA);
        unsigned b1 = __shfl(pp[2 * ks + 1][mP][1], sA);
        unsigned b2 = __shfl(pp[2 * ks + 1][mP][0], sB);
        unsigned b3 = __shfl(pp[2 * ks + 1][mP][1], sB);
        uint4v u;
        u.x = upper ? b0 : a0;
        u.y = upper ? b1 : a1;
        u.z = upper ? b2 : a2;
        u.w = upper ? b3 : a3;
        pa[mP] = __builtin_bit_cast(bf16x8, u);
      }
#pragma unroll
      for (int nd = 0; nd < 4; ++nd) {
        ushort8v bu;
#pragma unroll
        for (int j = 0; j < 8; ++j)
          bu[j] = vsm[(ks * 32 + g * 8 + j) * 72 + nd * 16 + l15];
        bf16x8 bv = __builtin_bit_cast(bf16x8, bu);
#pragma unroll
        for (int mP = 0; mP < 2; ++mP)
          oacc[mP][nd] = __builtin_amdgcn_mfma_f32_16x16x32_bf16(
              pa[mP], bv, oacc[mP][nd], 0, 0, 0);
      }
    }
    __syncthreads();
  }

  float inv_l[2][4];
#pragma unroll
  for (int mP = 0; mP < 2; ++mP)
#pragma unroll
    for (int r2 = 0; r2 < 4; ++r2)
      inv_l[mP][r2] = 1.f / __shfl(l_run[mP], g * 4 + r2);
#pragma unroll
  for (int mP = 0; mP < 2; ++mP)
#pragma unroll
    for (int nd = 0; nd < 4; ++nd)
#pragma unroll
      for (int r2 = 0; r2 < 4; ++r2) {
        const int t = q0 + wq0 + mP * 16 + g * 4 + r2;
        const int c = h_ * 64 + nd * 16 + l15;
        Og[((size_t)(b_ * T_SEQ + t)) * C_EMB + c] =
            f2bf(oacc[mP][nd][r2] * inv_l[mP][r2]);
      }
}

// ---------------------------------------------------------------- launch
extern "C" void kernel_launch(void* const* d_in, const int* in_sizes, int n_in,
                              void* d_out, int out_size, void* d_ws, size_t ws_size,
                              hipStream_t stream) {
  const float* x = (const float*)d_in[0];
  const float* w_attn = (const float*)d_in[1];
  const float* b_attn = (const float*)d_in[2];
  const float* w_proj = (const float*)d_in[3];
  const float* b_proj = (const float*)d_in[4];
  float* out = (float*)d_out;

  char* ws = (char*)d_ws;
  size_t off = 0;
  auto carve = [&](size_t bytes) -> void* {
    void* p = ws + off;
    off += (bytes + 255) & ~(size_t)255;
    return p;
  };
  unsigned short* xbf = (unsigned short*)carve((size_t)M_TOK * C_EMB * 2);
  unsigned short* wab = (unsigned short*)carve((size_t)N_QKV * C_EMB * 2);
  unsigned short* wpb = (unsigned short*)carve((size_t)C_EMB * C_EMB * 2);
  unsigned short* Qb = (unsigned short*)carve((size_t)B_SZ * NH_ * T_SEQ * HS_ * 2);
  unsigned short* Kb = (unsigned short*)carve((size_t)B_SZ * NH_ * T_SEQ * HS_ * 2);
  unsigned short* Vb = (unsigned short*)carve((size_t)B_SZ * NH_ * T_SEQ * HS_ * 2);
  unsigned short* Ob = (unsigned short*)carve((size_t)M_TOK * C_EMB * 2);

  cvt_f32_bf16<<<6144, 256, 0, stream>>>(x, xbf);        // 8192*768
  cvt_f32_bf16<<<1728, 256, 0, stream>>>(w_attn, wab);   // 2304*768
  cvt_f32_bf16<<<576, 256, 0, stream>>>(w_proj, wpb);    // 768*768

  gemm_bt_kernel<0><<<dim3(N_QKV / 128, M_TOK / 128), 256, 0, stream>>>(
      xbf, wab, b_attn, Qb, Kb, Vb, nullptr, C_EMB, N_QKV);

  flash_kernel<<<dim3(T_SEQ / 128, B_SZ * NH_), 256, 0, stream>>>(Qb, Kb, Vb, Ob);

  gemm_bt_kernel<1><<<dim3(C_EMB / 128, M_TOK / 128), 256, 0, stream>>>(
      Ob, wpb, b_proj, nullptr, nullptr, nullptr, out, C_EMB, C_EMB);
}

// Round 2
// 199.584 us; speedup vs baseline: 2.1296x; 2.1296x over previous
//
#include <hip/hip_runtime.h>
#include <hip/hip_bf16.h>

// Problem constants (fixed by the reference)
#define T_SEQ 4096
#define C_EMB 768
#define NH_ 12
#define HS_ 64
#define B_SZ 2
#define M_TOK 8192        // B*T
#define N_QKV 2304        // 3*C

typedef __attribute__((ext_vector_type(8))) __bf16 bf16x8;
typedef __attribute__((ext_vector_type(8))) unsigned short ushort8v;
typedef __attribute__((ext_vector_type(2))) unsigned int uint2v;
typedef __attribute__((ext_vector_type(4))) float f32x4;

__device__ __forceinline__ unsigned short f2bf(float f) {
  __hip_bfloat16 h = __float2bfloat16(f);
  return __builtin_bit_cast(unsigned short, h);
}

__device__ __forceinline__ unsigned int pack2bf(float lo, float hi) {
  return ((unsigned int)f2bf(hi) << 16) | (unsigned int)f2bf(lo);
}

// XOR swizzle: row-major [R][64] bf16 tile (128 B rows). Spreads the 16B slot
// across banks per row so b128 frag reads (fixed col, rows=lane&15) are
// conflict-free. Consistent on write+read (both-sides rule).
#define KSWZ(row, bytecol) ((((row) * 128) + ((bytecol) ^ (((row) & 7) << 4))))

// ---------------------------------------------------------------- converts
__global__ void cvt_f32_bf16(const float* __restrict__ in,
                             unsigned short* __restrict__ out) {
  int i = (blockIdx.x * 256 + threadIdx.x) * 4;
  float4 v = *reinterpret_cast<const float4*>(&in[i]);
  ushort4 o;
  o.x = f2bf(v.x); o.y = f2bf(v.y); o.z = f2bf(v.z); o.w = f2bf(v.w);
  *reinterpret_cast<ushort4*>(&out[i]) = o;
}

// ---------------------------------------------------------------- GEMM (B^T)
// C[M][N] = A[M][K] * Bw[N][K]^T + bias.  128x128 tile, 4 waves, BK=64.
// MODE 0: scatter into Q [bh][t][64] (scaled), K [bh][t][64], Vt [bh][d][t]
// MODE 1: fp32 out row-major [M][N]
template <int MODE>
__global__ __launch_bounds__(256) void gemm_bt_kernel(
    const unsigned short* __restrict__ A, const unsigned short* __restrict__ Bw,
    const float* __restrict__ bias, unsigned short* __restrict__ qo,
    unsigned short* __restrict__ ko, unsigned short* __restrict__ vo,
    float* __restrict__ fo, int Kdim, int Ndim) {
  __shared__ unsigned short as_[128 * 72];  // +8 pad: spread banks on frag reads
  __shared__ unsigned short bs_[128 * 72];
  const int tid = threadIdx.x;
  const int lane = tid & 63;
  const int wid = tid >> 6;
  const int g = lane >> 4;
  const int l15 = lane & 15;
  const int m0 = blockIdx.y * 128;
  const int n0 = blockIdx.x * 128;
  const int wm = (wid >> 1) * 64;
  const int wn = (wid & 1) * 64;

  f32x4 acc[4][4];
#pragma unroll
  for (int i = 0; i < 4; ++i)
#pragma unroll
    for (int j = 0; j < 4; ++j) acc[i][j] = (f32x4){0.f, 0.f, 0.f, 0.f};

  for (int k0 = 0; k0 < Kdim; k0 += 64) {
#pragma unroll
    for (int it = 0; it < 4; ++it) {
      int cid = tid + it * 256;
      int r = cid >> 3, c8 = (cid & 7) << 3;
      *reinterpret_cast<ushort8v*>(&as_[r * 72 + c8]) =
          *reinterpret_cast<const ushort8v*>(&A[(size_t)(m0 + r) * Kdim + k0 + c8]);
      *reinterpret_cast<ushort8v*>(&bs_[r * 72 + c8]) =
          *reinterpret_cast<const ushort8v*>(&Bw[(size_t)(n0 + r) * Kdim + k0 + c8]);
    }
    __syncthreads();
#pragma unroll
    for (int ks = 0; ks < 2; ++ks) {
      bf16x8 af[4], bfr[4];
#pragma unroll
      for (int mf = 0; mf < 4; ++mf)
        af[mf] = __builtin_bit_cast(bf16x8,
            *reinterpret_cast<const ushort8v*>(&as_[(wm + mf * 16 + l15) * 72 + ks * 32 + g * 8]));
#pragma unroll
      for (int nf = 0; nf < 4; ++nf)
        bfr[nf] = __builtin_bit_cast(bf16x8,
            *reinterpret_cast<const ushort8v*>(&bs_[(wn + nf * 16 + l15) * 72 + ks * 32 + g * 8]));
#pragma unroll
      for (int mf = 0; mf < 4; ++mf)
#pragma unroll
        for (int nf = 0; nf < 4; ++nf)
          acc[mf][nf] = __builtin_amdgcn_mfma_f32_16x16x32_bf16(
              af[mf], bfr[nf], acc[mf][nf], 0, 0, 0);
    }
    __syncthreads();
  }

#pragma unroll
  for (int mf = 0; mf < 4; ++mf)
#pragma unroll
    for (int nf = 0; nf < 4; ++nf) {
      const int n = n0 + wn + nf * 16 + l15;
      const float bval = bias[n];
      float v4[4];
#pragma unroll
      for (int r2 = 0; r2 < 4; ++r2) v4[r2] = acc[mf][nf][r2] + bval;
      const int mb = m0 + wm + mf * 16 + g * 4;   // 4-aligned row base
      if (MODE == 1) {
#pragma unroll
        for (int r2 = 0; r2 < 4; ++r2)
          fo[(size_t)(mb + r2) * Ndim + n] = v4[r2];
      } else {
        const int which = (n >= 1536) ? 2 : ((n >= 768) ? 1 : 0);
        const int c = n - which * 768;
        const int h = c >> 6, d = c & 63;
        const int bI = mb >> 12, t = mb & 4095;
        if (which == 0) {
          const size_t off = ((size_t)(bI * NH_ + h) * T_SEQ + t) * HS_ + d;
#pragma unroll
          for (int r2 = 0; r2 < 4; ++r2)
            qo[off + (size_t)r2 * HS_] = f2bf(v4[r2] * 0.125f);  // fold SCALE
        } else if (which == 1) {
          const size_t off = ((size_t)(bI * NH_ + h) * T_SEQ + t) * HS_ + d;
#pragma unroll
          for (int r2 = 0; r2 < 4; ++r2)
            ko[off + (size_t)r2 * HS_] = f2bf(v4[r2]);
        } else {
          // V transposed: Vt[bh][d][t] — 4 consecutive t → one 8B store
          const size_t off = ((size_t)(bI * NH_ + h) * HS_ + d) * T_SEQ + t;
          ushort4 o;
          o.x = f2bf(v4[0]); o.y = f2bf(v4[1]);
          o.z = f2bf(v4[2]); o.w = f2bf(v4[3]);
          *reinterpret_cast<ushort4*>(&vo[off]) = o;
        }
      }
    }
}

// ---------------------------------------------------------------- flash attn
// O-transposed flash. Per block: 128 q-rows of one (b,h); 4 waves x 32 tq.
// KV tiles of 64. St = mfma(K,Q) -> St[tk][tq] (softmax stats per-lane at
// col tq=lane&15). PV: O^T = mfma(Vt, P^T); P^T via wave-private LDS
// round-trip (8 ds_write_b64 + 4 ds_read_b128, XOR-swizzled).
__global__ __launch_bounds__(256, 3) void flash_kernel(
    const unsigned short* __restrict__ Qg, const unsigned short* __restrict__ Kg,
    const unsigned short* __restrict__ Vtg, unsigned short* __restrict__ Og) {
  __shared__ __align__(16) char ksm[8192];    // K tile [64][64] bf16, swizzled
  __shared__ __align__(16) char vtm[8192];    // Vt tile [64 d][64 t], swizzled
  __shared__ __align__(16) char pls[16384];   // P^T per wave [32 tq][64 tk]
  const int tid = threadIdx.x;
  const int lane = tid & 63;
  const int wid = tid >> 6;
  const int g = lane >> 4;
  const int l15 = lane & 15;

  // balanced triple mapping: CU's resident triple {767-c, 256+c, c} has
  // qt-sum (1023+c)/24 ~ const (+-11%); heavy tiles dispatched first.
  const int cc = blockIdx.x & 255, kk = blockIdx.x >> 8;
  const int m = (kk == 0) ? (767 - cc) : ((kk == 1) ? (256 + cc) : cc);
  const int qt = m / 24;
  const int bh = m - qt * 24;
  const int q0 = qt * 128;
  const int b_ = bh / NH_, h_ = bh % NH_;
  const size_t kqbase = (size_t)bh * T_SEQ * HS_;
  const size_t vtbase = (size_t)bh * HS_ * T_SEQ;
  const int wq0 = wid * 32;

  // Q fragments: loop-invariant, straight from global (no LDS)
  bf16x8 qf[2][2];
#pragma unroll
  for (int nf = 0; nf < 2; ++nf)
#pragma unroll
    for (int ks = 0; ks < 2; ++ks)
      qf[nf][ks] = __builtin_bit_cast(bf16x8,
          *reinterpret_cast<const ushort8v*>(
              &Qg[kqbase + (size_t)(q0 + wq0 + nf * 16 + l15) * HS_ + ks * 32 + g * 8]));

  float m_run[2] = {-1e30f, -1e30f};
  float l_run[2] = {0.f, 0.f};
  f32x4 oacc[2][4];
#pragma unroll
  for (int i = 0; i < 2; ++i)
#pragma unroll
    for (int j = 0; j < 4; ++j) oacc[i][j] = (f32x4){0.f, 0.f, 0.f, 0.f};

  char* pw = pls + wid * 4096;   // this wave's P^T region

  const int nkt = (q0 >> 6) + 2;                 // block KV-tile count
  const int myt = ((q0 + wq0 + 31) >> 6) + 1;    // this wave's needed tiles
  for (int kt = 0; kt < nkt; ++kt) {
    const int k0 = kt * 64;
    // ---- stage K and Vt tiles (reg-staged, XOR-swizzled LDS)
#pragma unroll
    for (int it = 0; it < 2; ++it) {
      int ci = tid + it * 256;
      int r = ci >> 3, s = (ci & 7) * 16;   // s = byte col
      ushort8v kv = *reinterpret_cast<const ushort8v*>(
          &Kg[kqbase + (size_t)(k0 + r) * HS_ + (s >> 1)]);
      *reinterpret_cast<ushort8v*>(ksm + KSWZ(r, s)) = kv;
      ushort8v vv = *reinterpret_cast<const ushort8v*>(
          &Vtg[vtbase + (size_t)r * T_SEQ + k0 + (s >> 1)]);
      *reinterpret_cast<ushort8v*>(vtm + KSWZ(r, s)) = vv;
    }
    __syncthreads();

    if (kt < myt) {
      // ---- QK^T (swapped): St[tk][tq]
      f32x4 st[4][2];
#pragma unroll
      for (int i = 0; i < 4; ++i)
#pragma unroll
        for (int j = 0; j < 2; ++j) st[i][j] = (f32x4){0.f, 0.f, 0.f, 0.f};
#pragma unroll
      for (int ks = 0; ks < 2; ++ks) {
        bf16x8 kf[4];
#pragma unroll
        for (int mf = 0; mf < 4; ++mf)
          kf[mf] = __builtin_bit_cast(bf16x8,
              *reinterpret_cast<const ushort8v*>(
                  ksm + KSWZ(mf * 16 + l15, ks * 64 + g * 16)));
#pragma unroll
        for (int mf = 0; mf < 4; ++mf)
#pragma unroll
          for (int nf = 0; nf < 2; ++nf)
            st[mf][nf] = __builtin_amdgcn_mfma_f32_16x16x32_bf16(
                kf[mf], qf[nf][ks], st[mf][nf], 0, 0, 0);
      }

      // ---- causal mask (wave-uniform branch)
      if (k0 + 63 > q0 + wq0) {
#pragma unroll
        for (int mf = 0; mf < 4; ++mf)
#pragma unroll
          for (int nf = 0; nf < 2; ++nf)
#pragma unroll
            for (int r2 = 0; r2 < 4; ++r2) {
              const int tk = k0 + mf * 16 + g * 4 + r2;
              const int tq = q0 + wq0 + nf * 16 + l15;
              if (tk > tq) st[mf][nf][r2] = -1e30f;
            }
      }

      // ---- online softmax; stats are per-lane for column tq = nf*16+l15
      float alpha[2];
#pragma unroll
      for (int nf = 0; nf < 2; ++nf) {
        float mx = -1e30f;
#pragma unroll
        for (int mf = 0; mf < 4; ++mf)
#pragma unroll
          for (int r2 = 0; r2 < 4; ++r2) mx = fmaxf(mx, st[mf][nf][r2]);
        mx = fmaxf(mx, __shfl_xor(mx, 16));
        mx = fmaxf(mx, __shfl_xor(mx, 32));
        const float mnew = fmaxf(m_run[nf], mx);
        alpha[nf] = __expf(m_run[nf] - mnew);
        float ssum = 0.f;
#pragma unroll
        for (int mf = 0; mf < 4; ++mf)
#pragma unroll
          for (int r2 = 0; r2 < 4; ++r2) {
            const float p = __expf(st[mf][nf][r2] - mnew);
            st[mf][nf][r2] = p;
            ssum += p;
          }
        ssum += __shfl_xor(ssum, 16);
        ssum += __shfl_xor(ssum, 32);
        l_run[nf] = l_run[nf] * alpha[nf] + ssum;
        m_run[nf] = mnew;
      }

      // ---- rescale O^T accumulators: per-lane alpha (col = tq) — no shfl
#pragma unroll
      for (int nf = 0; nf < 2; ++nf)
#pragma unroll
        for (int nd = 0; nd < 4; ++nd)
#pragma unroll
          for (int r2 = 0; r2 < 4; ++r2) oacc[nf][nd][r2] *= alpha[nf];

      // ---- write P^T [tq][tk] to wave-private LDS (8 x ds_write_b64)
#pragma unroll
      for (int mf = 0; mf < 4; ++mf)
#pragma unroll
        for (int nf = 0; nf < 2; ++nf) {
          uint2v w;
          w.x = pack2bf(st[mf][nf][0], st[mf][nf][1]);
          w.y = pack2bf(st[mf][nf][2], st[mf][nf][3]);
          *reinterpret_cast<uint2v*>(
              pw + KSWZ(nf * 16 + l15, mf * 32 + g * 8)) = w;
        }

      // ---- PV: O^T[d][tq] += mfma(Vt-frag, P^T-frag)
#pragma unroll
      for (int ks = 0; ks < 2; ++ks) {
        bf16x8 vt[4], pf[2];
#pragma unroll
        for (int nd = 0; nd < 4; ++nd)
          vt[nd] = __builtin_bit_cast(bf16x8,
              *reinterpret_cast<const ushort8v*>(
                  vtm + KSWZ(nd * 16 + l15, ks * 64 + g * 16)));
#pragma unroll
        for (int nf = 0; nf < 2; ++nf)
          pf[nf] = __builtin_bit_cast(bf16x8,
              *reinterpret_cast<const ushort8v*>(
                  pw + KSWZ(nf * 16 + l15, ks * 64 + g * 16)));
#pragma unroll
        for (int nf = 0; nf < 2; ++nf)
#pragma unroll
          for (int nd = 0; nd < 4; ++nd)
            oacc[nf][nd] = __builtin_amdgcn_mfma_f32_16x16x32_bf16(
                vt[nd], pf[nf], oacc[nf][nd], 0, 0, 0);
      }
    }
    __syncthreads();
  }

  // ---- epilogue: normalize per-lane (col=tq), store O^T -> Og[t][c]
#pragma unroll
  for (int nf = 0; nf < 2; ++nf) {
    const float invl = 1.f / l_run[nf];
    const int t = q0 + wq0 + nf * 16 + l15;
#pragma unroll
    for (int nd = 0; nd < 4; ++nd) {
      ushort4 o;
      o.x = f2bf(oacc[nf][nd][0] * invl);
      o.y = f2bf(oacc[nf][nd][1] * invl);
      o.z = f2bf(oacc[nf][nd][2] * invl);
      o.w = f2bf(oacc[nf][nd][3] * invl);
      *reinterpret_cast<ushort4*>(
          &Og[((size_t)(b_ * T_SEQ + t)) * C_EMB + h_ * 64 + nd * 16 + g * 4]) = o;
    }
  }
}

// ---------------------------------------------------------------- launch
extern "C" void kernel_launch(void* const* d_in, const int* in_sizes, int n_in,
                              void* d_out, int out_size, void* d_ws, size_t ws_size,
                              hipStream_t stream) {
  const float* x = (const float*)d_in[0];
  const float* w_attn = (const float*)d_in[1];
  const float* b_attn = (const float*)d_in[2];
  const float* w_proj = (const float*)d_in[3];
  const float* b_proj = (const float*)d_in[4];
  float* out = (float*)d_out;

  char* ws = (char*)d_ws;
  size_t off = 0;
  auto carve = [&](size_t bytes) -> void* {
    void* p = ws + off;
    off += (bytes + 255) & ~(size_t)255;
    return p;
  };
  unsigned short* xbf = (unsigned short*)carve((size_t)M_TOK * C_EMB * 2);
  unsigned short* wab = (unsigned short*)carve((size_t)N_QKV * C_EMB * 2);
  unsigned short* wpb = (unsigned short*)carve((size_t)C_EMB * C_EMB * 2);
  unsigned short* Qb = (unsigned short*)carve((size_t)B_SZ * NH_ * T_SEQ * HS_ * 2);
  unsigned short* Kb = (unsigned short*)carve((size_t)B_SZ * NH_ * T_SEQ * HS_ * 2);
  unsigned short* Vtb = (unsigned short*)carve((size_t)B_SZ * NH_ * T_SEQ * HS_ * 2);
  unsigned short* Ob = (unsigned short*)carve((size_t)M_TOK * C_EMB * 2);

  cvt_f32_bf16<<<6144, 256, 0, stream>>>(x, xbf);        // 8192*768
  cvt_f32_bf16<<<1728, 256, 0, stream>>>(w_attn, wab);   // 2304*768
  cvt_f32_bf16<<<576, 256, 0, stream>>>(w_proj, wpb);    // 768*768

  gemm_bt_kernel<0><<<dim3(N_QKV / 128, M_TOK / 128), 256, 0, stream>>>(
      xbf, wab, b_attn, Qb, Kb, Vtb, nullptr, C_EMB, N_QKV);

  flash_kernel<<<dim3(768), 256, 0, stream>>>(Qb, Kb, Vtb, Ob);

  gemm_bt_kernel<1><<<dim3(C_EMB / 128, M_TOK / 128), 256, 0, stream>>>(
      Ob, wpb, b_proj, nullptr, nullptr, nullptr, out, C_EMB, C_EMB);
}